// Round 3
// baseline (369.031 us; speedup 1.0000x reference)
//
#include <hip/hip_runtime.h>
#include <hip/hip_bf16.h>
#include <math.h>

typedef __attribute__((ext_vector_type(8))) short short8;
typedef __attribute__((ext_vector_type(4))) float float4v;

#define C_DIM 192
#define NHEADS 6
#define NTOK 50176

__device__ __forceinline__ float bf2f(unsigned short u){
  union { unsigned int i; float f; } x; x.i = ((unsigned int)u) << 16; return x.f;
}
__device__ __forceinline__ unsigned short f2bf(float f){
  union { float f; unsigned int i; } x; x.f = f;
  unsigned int r = x.i + 0x7fff + ((x.i >> 16) & 1);
  return (unsigned short)(r >> 16);
}

// window-layout row r -> natural token index (same mapping for LN1 gather and proj scatter)
__device__ __forceinline__ int nat_token(int r){
  int win = r / 49, n = r - win * 49;
  int b = win >> 6, rem = win & 63;
  int hs = (rem >> 3) * 7 + n / 7;
  int ws = (rem & 7) * 7 + n % 7;
  int h = hs + 3; if (h >= 56) h -= 56;
  int w = ws + 3; if (w >= 56) w -= 56;
  return (b * 56 + h) * 56 + w;
}

// ---------------- weight transpose + f32->bf16: in[R][C] fp32 -> out[C][R] bf16 ----------------
__global__ void transpose_kernel(const float* __restrict__ in,
                                 unsigned short* __restrict__ out, int R, int Cc){
  int idx = blockIdx.x * 256 + threadIdx.x;
  if (idx < R * Cc){ int r = idx / Cc, c = idx - r * Cc; out[(long)c * R + r] = f2bf(in[idx]); }
}

// ---------------- LN1 + shift + window partition (gather): fp32 in -> bf16 out ----------------
__global__ __launch_bounds__(256) void ln1_kernel(const float* __restrict__ x,
                                                  const float* __restrict__ w,
                                                  const float* __restrict__ b,
                                                  unsigned short* __restrict__ out){
  int wave = threadIdx.x >> 6, lane = threadIdx.x & 63;
  int r = blockIdx.x * 4 + wave;            // dest row, window layout
  int src = nat_token(r);
  const float* xp = x + (long)src * C_DIM;
  float v0 = xp[lane], v1 = xp[lane + 64], v2 = xp[lane + 128];
  float s = v0 + v1 + v2, s2 = v0*v0 + v1*v1 + v2*v2;
  for (int m = 32; m >= 1; m >>= 1){ s += __shfl_xor(s, m, 64); s2 += __shfl_xor(s2, m, 64); }
  float mean = s * (1.f/192.f);
  float var  = s2 * (1.f/192.f) - mean*mean;
  float rs = rsqrtf(var + 1e-5f);
  unsigned short* op = out + (long)r * C_DIM;
  op[lane]       = f2bf((v0-mean)*rs*w[lane]       + b[lane]);
  op[lane + 64]  = f2bf((v1-mean)*rs*w[lane + 64]  + b[lane + 64]);
  op[lane + 128] = f2bf((v2-mean)*rs*w[lane + 128] + b[lane + 128]);
}

// ---------------- LN2: fp32 y (in d_out, natural order) -> bf16 out ----------------
__global__ __launch_bounds__(256) void ln2_kernel(const float* __restrict__ y,
                                                  const float* __restrict__ w,
                                                  const float* __restrict__ b,
                                                  unsigned short* __restrict__ out){
  int wave = threadIdx.x >> 6, lane = threadIdx.x & 63;
  int r = blockIdx.x * 4 + wave;
  const float* yp = y + (long)r * C_DIM;
  float v0 = yp[lane], v1 = yp[lane + 64], v2 = yp[lane + 128];
  float s = v0 + v1 + v2, s2 = v0*v0 + v1*v1 + v2*v2;
  for (int m = 32; m >= 1; m >>= 1){ s += __shfl_xor(s, m, 64); s2 += __shfl_xor(s2, m, 64); }
  float mean = s * (1.f/192.f);
  float var  = s2 * (1.f/192.f) - mean*mean;
  float rs = rsqrtf(var + 1e-5f);
  unsigned short* op = out + (long)r * C_DIM;
  op[lane]       = f2bf((v0-mean)*rs*w[lane]       + b[lane]);
  op[lane + 64]  = f2bf((v1-mean)*rs*w[lane + 64]  + b[lane + 64]);
  op[lane + 128] = f2bf((v2-mean)*rs*w[lane + 128] + b[lane + 128]);
}

// ---------------- window attention: 1 wave = 1 (window, head), bf16 qkv ----------------
__global__ __launch_bounds__(256) void attn_kernel(const unsigned short* __restrict__ qkv,
                                                   unsigned short* __restrict__ o){
  __shared__ unsigned short kv[4][2][49 * 32];   // [wave][k|v][n*32+d]
  int wave = threadIdx.x >> 6, lane = threadIdx.x & 63;
  int wid = blockIdx.x * 4 + wave;
  int win = wid / NHEADS, head = wid - win * NHEADS;
  long base = (long)win * 49 * 576 + head * 32;

  for (int t = lane; t < 196; t += 64){           // 196 8-elem vectors per matrix
    int n = t >> 2, d = (t & 3) * 8;
    *(uint4*)&kv[wave][0][n * 32 + d] = *(const uint4*)&qkv[base + 192 + (long)n * 576 + d];
    *(uint4*)&kv[wave][1][n * 32 + d] = *(const uint4*)&qkv[base + 384 + (long)n * 576 + d];
  }
  int j = lane < 49 ? lane : 48;
  float q[32];
  {
    const unsigned short* qp = &qkv[base + (long)j * 576];
    #pragma unroll
    for (int d8 = 0; d8 < 4; d8++){
      uint4 u = *(const uint4*)&qp[d8 * 8];
      const unsigned short* us = (const unsigned short*)&u;
      #pragma unroll
      for (int e = 0; e < 8; e++) q[d8*8+e] = bf2f(us[e]);
    }
  }
  __syncthreads();

  float s[49];
  #pragma unroll 1
  for (int k = 0; k < 49; k++){
    float acc = 0.f;
    #pragma unroll
    for (int d8 = 0; d8 < 4; d8++){
      uint4 u = *(const uint4*)&kv[wave][0][k * 32 + d8 * 8];
      const unsigned short* us = (const unsigned short*)&u;
      #pragma unroll
      for (int e = 0; e < 8; e++) acc += q[d8*8+e] * bf2f(us[e]);
    }
    s[k] = acc * 0.17677669529663687f;     // 1/sqrt(32)
  }
  float m = s[0];
  #pragma unroll
  for (int k = 1; k < 49; k++) m = fmaxf(m, s[k]);
  float l = 0.f;
  #pragma unroll
  for (int k = 0; k < 49; k++){ s[k] = __expf(s[k] - m); l += s[k]; }
  float inv = 1.f / l;

  float oacc[32];
  #pragma unroll
  for (int d = 0; d < 32; d++) oacc[d] = 0.f;
  #pragma unroll 1
  for (int k = 0; k < 49; k++){
    float p = s[k] * inv;
    #pragma unroll
    for (int d8 = 0; d8 < 4; d8++){
      uint4 u = *(const uint4*)&kv[wave][1][k * 32 + d8 * 8];
      const unsigned short* us = (const unsigned short*)&u;
      #pragma unroll
      for (int e = 0; e < 8; e++) oacc[d8*8+e] += p * bf2f(us[e]);
    }
  }
  if (lane < 49){
    unsigned short* op = &o[((long)win * 49 + lane) * C_DIM + head * 32];
    #pragma unroll
    for (int d8 = 0; d8 < 4; d8++){
      union { unsigned short us[8]; uint4 u; } pk;
      #pragma unroll
      for (int e = 0; e < 8; e++) pk.us[e] = f2bf(oacc[d8*8+e]);
      *(uint4*)&op[d8 * 8] = pk.u;
    }
  }
}

// ---------------- generic MFMA GEMM: A[M,K]bf16 x Bt[N,K]bf16^T + bias(fp32), fused epilogues ----
// EPI 0: qkv  -> Cout bf16 [M,N]
// EPI 1: proj -> Fout[nat(r)*192+c] = Xres[nat(r)*192+c] + acc+bias   (fp32 y into d_out)
// EPI 2: mlp1 -> Cout = bf16(gelu(acc+bias))
// EPI 3: mlp2 -> Fout[r*192+c] = Xres[r*192+c] + acc+bias  (Xres==Fout==d_out, per-elem RMW)
template<int EPI>
__global__ __launch_bounds__(256) void gemm_kernel(const unsigned short* __restrict__ A,
                                                   const unsigned short* __restrict__ Bt,
                                                   const float* __restrict__ bias,
                                                   unsigned short* __restrict__ Cout,
                                                   float* __restrict__ Fout,
                                                   const float* __restrict__ Xres,
                                                   int N, int K){
  __shared__ unsigned short As[128][72];   // +8 pad: row stride 144B = 9*16B
  __shared__ unsigned short Bs[64][72];
  int tid = threadIdx.x;
  int wave = tid >> 6, lane = tid & 63, quad = lane >> 4, l16 = lane & 15;
  int wm = (wave >> 1) * 64, wn = (wave & 1) * 32;
  float4v acc[4][2];
  #pragma unroll
  for (int i = 0; i < 4; i++)
    #pragma unroll
    for (int jj = 0; jj < 2; jj++) acc[i][jj] = (float4v)0.f;

  long arow0 = (long)blockIdx.x * 128;
  long brow0 = (long)blockIdx.y * 64;

  for (int k0 = 0; k0 < K; k0 += 64){
    #pragma unroll
    for (int i = 0; i < 4; i++){
      int linear = i * 2048 + tid * 8;
      int row = linear >> 6, col = linear & 63;
      *(uint4*)&As[row][col] = *(const uint4*)&A[(arow0 + row) * K + k0 + col];
    }
    #pragma unroll
    for (int i = 0; i < 2; i++){
      int linear = i * 2048 + tid * 8;
      int row = linear >> 6, col = linear & 63;
      *(uint4*)&Bs[row][col] = *(const uint4*)&Bt[(brow0 + row) * K + k0 + col];
    }
    __syncthreads();
    #pragma unroll
    for (int kk = 0; kk < 64; kk += 32){
      short8 a[4], b[2];
      #pragma unroll
      for (int mi = 0; mi < 4; mi++) a[mi] = *(const short8*)&As[wm + mi*16 + l16][kk + quad*8];
      #pragma unroll
      for (int ni = 0; ni < 2; ni++) b[ni] = *(const short8*)&Bs[wn + ni*16 + l16][kk + quad*8];
      #pragma unroll
      for (int mi = 0; mi < 4; mi++)
        #pragma unroll
        for (int ni = 0; ni < 2; ni++)
          acc[mi][ni] = __builtin_amdgcn_mfma_f32_16x16x32_bf16(a[mi], b[ni], acc[mi][ni], 0, 0, 0);
    }
    __syncthreads();
  }

  #pragma unroll
  for (int mi = 0; mi < 4; mi++){
    #pragma unroll
    for (int reg = 0; reg < 4; reg++){
      long r = arow0 + wm + mi*16 + quad*4 + reg;   // C/D: row = quad*4+reg, col = l16
      #pragma unroll
      for (int ni = 0; ni < 2; ni++){
        int c = (int)(brow0 + wn + ni*16 + l16);
        float v = acc[mi][ni][reg] + bias[c];
        if (EPI == 0){
          Cout[r * N + c] = f2bf(v);
        } else if (EPI == 1){
          int t = nat_token((int)r);
          long idx = (long)t * C_DIM + c;
          Fout[idx] = Xres[idx] + v;
        } else if (EPI == 2){
          float g = 0.5f * v * (1.f + erff(v * 0.70710678118654752f));
          Cout[r * N + c] = f2bf(g);
        } else {
          long idx = r * C_DIM + c;
          Fout[idx] = Xres[idx] + v;
        }
      }
    }
  }
}

extern "C" void kernel_launch(void* const* d_in, const int* in_sizes, int n_in,
                              void* d_out, int out_size, void* d_ws, size_t ws_size,
                              hipStream_t stream){
  const float* x      = (const float*)d_in[0];
  const float* ln1_w  = (const float*)d_in[1];
  const float* ln1_b  = (const float*)d_in[2];
  const float* qkv_w  = (const float*)d_in[3];
  const float* qkv_b  = (const float*)d_in[4];
  const float* proj_w = (const float*)d_in[5];
  const float* proj_b = (const float*)d_in[6];
  const float* ln2_w  = (const float*)d_in[7];
  const float* ln2_b  = (const float*)d_in[8];
  const float* mlp_w1 = (const float*)d_in[9];
  const float* mlp_b1 = (const float*)d_in[10];
  const float* mlp_w2 = (const float*)d_in[11];
  const float* mlp_b2 = (const float*)d_in[12];
  float* out = (float*)d_out;   // fp32 output; also hosts fp32 residual y between EPI1 and EPI3

  // --- aliased workspace (~92.7 MiB), all internal buffers bf16 ---
  // [0, 884736)          transposed bf16 weights
  // [884736, 20152320)   R1: xw -> obuf -> hn   (disjoint lifetimes)
  // [20152320, 97222656) R0: qkv -> hbuf        (disjoint lifetimes)
  char* ws = (char*)d_ws;
  unsigned short* qkv_wt = (unsigned short*)(ws);               // [576][192]
  unsigned short* proj_wt= (unsigned short*)(ws + 221184);      // [192][192]
  unsigned short* w1t    = (unsigned short*)(ws + 294912);      // [768][192]
  unsigned short* w2t    = (unsigned short*)(ws + 589824);      // [192][768]
  unsigned short* R1     = (unsigned short*)(ws + 884736);      // 50176x192 bf16
  unsigned short* R0     = (unsigned short*)(ws + 20152320);    // up to 50176x768 bf16

  unsigned short* xw   = R1;
  unsigned short* obuf = R1;
  unsigned short* hn   = R1;
  unsigned short* qkv  = R0;
  unsigned short* hbuf = R0;

  transpose_kernel<<<(110592 + 255) / 256, 256, 0, stream>>>(qkv_w, qkv_wt, 192, 576);
  transpose_kernel<<<(36864  + 255) / 256, 256, 0, stream>>>(proj_w, proj_wt, 192, 192);
  transpose_kernel<<<(147456 + 255) / 256, 256, 0, stream>>>(mlp_w1, w1t, 192, 768);
  transpose_kernel<<<(147456 + 255) / 256, 256, 0, stream>>>(mlp_w2, w2t, 768, 192);

  ln1_kernel<<<NTOK / 4, 256, 0, stream>>>(x, ln1_w, ln1_b, xw);
  gemm_kernel<0><<<dim3(392, 9),  256, 0, stream>>>(xw, qkv_wt, qkv_b, qkv, nullptr, nullptr, 576, 192);
  attn_kernel<<<(NTOK / 49) * NHEADS / 4, 256, 0, stream>>>(qkv, obuf);
  gemm_kernel<1><<<dim3(392, 3),  256, 0, stream>>>(obuf, proj_wt, proj_b, nullptr, out, x, 192, 192);
  ln2_kernel<<<NTOK / 4, 256, 0, stream>>>(out, ln2_w, ln2_b, hn);
  gemm_kernel<2><<<dim3(392, 12), 256, 0, stream>>>(hn, w1t, mlp_b1, hbuf, nullptr, nullptr, 768, 192);
  gemm_kernel<3><<<dim3(392, 3),  256, 0, stream>>>(hbuf, w2t, mlp_b2, nullptr, out, out, 192, 768);
}

// Round 4
// 284.326 us; speedup vs baseline: 1.2979x; 1.2979x over previous
//
#include <hip/hip_runtime.h>
#include <hip/hip_bf16.h>
#include <math.h>

typedef __attribute__((ext_vector_type(8))) short short8;
typedef __attribute__((ext_vector_type(4))) float float4v;

#define C_DIM 192
#define NHEADS 6
#define NTOK 50176

__device__ __forceinline__ float bf2f(unsigned short u){
  union { unsigned int i; float f; } x; x.i = ((unsigned int)u) << 16; return x.f;
}
__device__ __forceinline__ unsigned short f2bf(float f){
  union { float f; unsigned int i; } x; x.f = f;
  unsigned int r = x.i + 0x7fff + ((x.i >> 16) & 1);
  return (unsigned short)(r >> 16);
}

// window-layout row r -> natural token index (same mapping for LN1 gather and proj scatter)
__device__ __forceinline__ int nat_token(int r){
  int win = r / 49, n = r - win * 49;
  int b = win >> 6, rem = win & 63;
  int hs = (rem >> 3) * 7 + n / 7;
  int ws = (rem & 7) * 7 + n % 7;
  int h = hs + 3; if (h >= 56) h -= 56;
  int w = ws + 3; if (w >= 56) w -= 56;
  return (b * 56 + h) * 56 + w;
}

// ---------------- weight transpose + f32->bf16: in[R][C] fp32 -> out[C][R] bf16 ----------------
__global__ void transpose_kernel(const float* __restrict__ in,
                                 unsigned short* __restrict__ out, int R, int Cc){
  int idx = blockIdx.x * 256 + threadIdx.x;
  if (idx < R * Cc){ int r = idx / Cc, c = idx - r * Cc; out[(long)c * R + r] = f2bf(in[idx]); }
}

// ---------------- LN1 + shift + window partition (gather): fp32 in -> bf16 out ----------------
__global__ __launch_bounds__(256) void ln1_kernel(const float* __restrict__ x,
                                                  const float* __restrict__ w,
                                                  const float* __restrict__ b,
                                                  unsigned short* __restrict__ out){
  int wave = threadIdx.x >> 6, lane = threadIdx.x & 63;
  int r = blockIdx.x * 4 + wave;            // dest row, window layout
  int src = nat_token(r);
  const float* xp = x + (long)src * C_DIM;
  float v0 = xp[lane], v1 = xp[lane + 64], v2 = xp[lane + 128];
  float s = v0 + v1 + v2, s2 = v0*v0 + v1*v1 + v2*v2;
  for (int m = 32; m >= 1; m >>= 1){ s += __shfl_xor(s, m, 64); s2 += __shfl_xor(s2, m, 64); }
  float mean = s * (1.f/192.f);
  float var  = s2 * (1.f/192.f) - mean*mean;
  float rs = rsqrtf(var + 1e-5f);
  unsigned short* op = out + (long)r * C_DIM;
  op[lane]       = f2bf((v0-mean)*rs*w[lane]       + b[lane]);
  op[lane + 64]  = f2bf((v1-mean)*rs*w[lane + 64]  + b[lane + 64]);
  op[lane + 128] = f2bf((v2-mean)*rs*w[lane + 128] + b[lane + 128]);
}

// ---------------- LN2: fp32 y (in d_out, natural order) -> bf16 out ----------------
__global__ __launch_bounds__(256) void ln2_kernel(const float* __restrict__ y,
                                                  const float* __restrict__ w,
                                                  const float* __restrict__ b,
                                                  unsigned short* __restrict__ out){
  int wave = threadIdx.x >> 6, lane = threadIdx.x & 63;
  int r = blockIdx.x * 4 + wave;
  const float* yp = y + (long)r * C_DIM;
  float v0 = yp[lane], v1 = yp[lane + 64], v2 = yp[lane + 128];
  float s = v0 + v1 + v2, s2 = v0*v0 + v1*v1 + v2*v2;
  for (int m = 32; m >= 1; m >>= 1){ s += __shfl_xor(s, m, 64); s2 += __shfl_xor(s2, m, 64); }
  float mean = s * (1.f/192.f);
  float var  = s2 * (1.f/192.f) - mean*mean;
  float rs = rsqrtf(var + 1e-5f);
  unsigned short* op = out + (long)r * C_DIM;
  op[lane]       = f2bf((v0-mean)*rs*w[lane]       + b[lane]);
  op[lane + 64]  = f2bf((v1-mean)*rs*w[lane + 64]  + b[lane + 64]);
  op[lane + 128] = f2bf((v2-mean)*rs*w[lane + 128] + b[lane + 128]);
}

// ---------------- MFMA window attention: 1 wave = 1 (window, head) ----------------
// QK^T: A=Q rows (direct global frag loads), B=K rows (direct). S in C-layout regs.
// softmax: shift-invariant (no max pass; clamp 80), row-sum via 4 shfl_xor over l16 group.
// P -> LDS (stride 72 for 16B-aligned b128 reads) -> A-frags. V^T frags: 8 scalar global loads.
__global__ __launch_bounds__(256) void attn_kernel(const unsigned short* __restrict__ qkv,
                                                   unsigned short* __restrict__ o){
  __shared__ unsigned short pbuf[4][64][72];
  int wave = threadIdx.x >> 6, lane = threadIdx.x & 63;
  int quad = lane >> 4, l16 = lane & 15;
  int wid = blockIdx.x * 4 + wave;
  int win = wid / NHEADS, head = wid - win * NHEADS;
  const unsigned short* qp = qkv + (long)win * 49 * 576 + head * 32;
  const unsigned short* kp = qp + 192;
  const unsigned short* vp = qp + 384;

  // ---- QK^T ----
  short8 qa[4], kb[4];
  #pragma unroll
  for (int mi = 0; mi < 4; mi++){
    int m = mi * 16 + l16; if (m > 48) m = 48;       // clamped rows discarded at output
    qa[mi] = *(const short8*)&qp[(long)m * 576 + quad * 8];
  }
  #pragma unroll
  for (int ni = 0; ni < 4; ni++){
    int n = ni * 16 + l16; if (n > 48) n = 48;       // clamped cols masked in softmax
    kb[ni] = *(const short8*)&kp[(long)n * 576 + quad * 8];
  }
  float4v S[4][4];
  #pragma unroll
  for (int mi = 0; mi < 4; mi++)
    #pragma unroll
    for (int ni = 0; ni < 4; ni++) S[mi][ni] = (float4v)0.f;
  #pragma unroll
  for (int mi = 0; mi < 4; mi++)
    #pragma unroll
    for (int ni = 0; ni < 4; ni++)
      S[mi][ni] = __builtin_amdgcn_mfma_f32_16x16x32_bf16(qa[mi], kb[ni], S[mi][ni], 0, 0, 0);

  // ---- softmax + P to LDS ----
  #pragma unroll
  for (int mi = 0; mi < 4; mi++){
    #pragma unroll
    for (int r = 0; r < 4; r++){
      float e[4];
      float sum = 0.f;
      #pragma unroll
      for (int ni = 0; ni < 4; ni++){
        int n = ni * 16 + l16;
        float s = S[mi][ni][r] * 0.17677669529663687f;   // 1/sqrt(32)
        s = fminf(s, 80.f);
        float ev = (n <= 48) ? __expf(s) : 0.f;
        e[ni] = ev; sum += ev;
      }
      sum += __shfl_xor(sum, 1, 64);
      sum += __shfl_xor(sum, 2, 64);
      sum += __shfl_xor(sum, 4, 64);
      sum += __shfl_xor(sum, 8, 64);
      float inv = 1.f / sum;
      int m = mi * 16 + quad * 4 + r;
      #pragma unroll
      for (int ni = 0; ni < 4; ni++)
        pbuf[wave][m][ni * 16 + l16] = f2bf(e[ni] * inv);
    }
  }
  __syncthreads();   // wave-private pbuf; barrier is belt-and-braces for DS ordering

  // ---- V^T fragments (8 scalar global loads each; rows k>48 clamped, P there = 0) ----
  short8 vb[2][2];
  #pragma unroll
  for (int kk2 = 0; kk2 < 2; kk2++){
    #pragma unroll
    for (int ni = 0; ni < 2; ni++){
      union { unsigned short us[8]; short8 v8; } u;
      #pragma unroll
      for (int j = 0; j < 8; j++){
        int k = kk2 * 32 + quad * 8 + j; if (k > 48) k = 48;
        u.us[j] = vp[(long)k * 576 + ni * 16 + l16];
      }
      vb[kk2][ni] = u.v8;
    }
  }

  // ---- PV ----
  float4v O[4][2];
  #pragma unroll
  for (int mi = 0; mi < 4; mi++)
    #pragma unroll
    for (int ni = 0; ni < 2; ni++) O[mi][ni] = (float4v)0.f;
  #pragma unroll
  for (int kk2 = 0; kk2 < 2; kk2++){
    short8 pa[4];
    #pragma unroll
    for (int mi = 0; mi < 4; mi++)
      pa[mi] = *(const short8*)&pbuf[wave][mi * 16 + l16][kk2 * 32 + quad * 8];
    #pragma unroll
    for (int mi = 0; mi < 4; mi++)
      #pragma unroll
      for (int ni = 0; ni < 2; ni++)
        O[mi][ni] = __builtin_amdgcn_mfma_f32_16x16x32_bf16(pa[mi], vb[kk2][ni], O[mi][ni], 0, 0, 0);
  }

  // ---- write O (C-layout: row=quad*4+reg+16mi, col=d=ni*16+l16) ----
  #pragma unroll
  for (int mi = 0; mi < 4; mi++){
    int m0 = mi * 16 + quad * 4;
    #pragma unroll
    for (int r = 0; r < 4; r++){
      if (m0 + r <= 48){
        #pragma unroll
        for (int ni = 0; ni < 2; ni++)
          o[((long)win * 49 + m0 + r) * C_DIM + head * 32 + ni * 16 + l16] = f2bf(O[mi][ni][r]);
      }
    }
  }
}

// ---------------- generic MFMA GEMM: A[M,K]bf16 x Bt[N,K]bf16^T + bias(fp32), fused epilogues ----
// EPI 0: qkv  -> Cout bf16 [M,N]
// EPI 1: proj -> Fout[nat(r)*192+c] = Xres[nat(r)*192+c] + acc+bias   (fp32 y into d_out)
// EPI 2: mlp1 -> Cout = bf16(gelu(acc+bias))
// EPI 3: mlp2 -> Fout[r*192+c] = Xres[r*192+c] + acc+bias  (Xres==Fout==d_out, per-elem RMW)
template<int EPI>
__global__ __launch_bounds__(256) void gemm_kernel(const unsigned short* __restrict__ A,
                                                   const unsigned short* __restrict__ Bt,
                                                   const float* __restrict__ bias,
                                                   unsigned short* __restrict__ Cout,
                                                   float* __restrict__ Fout,
                                                   const float* __restrict__ Xres,
                                                   int N, int K){
  __shared__ unsigned short As[128][72];   // +8 pad: row stride 144B = 9*16B
  __shared__ unsigned short Bs[64][72];
  int tid = threadIdx.x;
  int wave = tid >> 6, lane = tid & 63, quad = lane >> 4, l16 = lane & 15;
  int wm = (wave >> 1) * 64, wn = (wave & 1) * 32;
  float4v acc[4][2];
  #pragma unroll
  for (int i = 0; i < 4; i++)
    #pragma unroll
    for (int jj = 0; jj < 2; jj++) acc[i][jj] = (float4v)0.f;

  long arow0 = (long)blockIdx.x * 128;
  long brow0 = (long)blockIdx.y * 64;

  for (int k0 = 0; k0 < K; k0 += 64){
    #pragma unroll
    for (int i = 0; i < 4; i++){
      int linear = i * 2048 + tid * 8;
      int row = linear >> 6, col = linear & 63;
      *(uint4*)&As[row][col] = *(const uint4*)&A[(arow0 + row) * K + k0 + col];
    }
    #pragma unroll
    for (int i = 0; i < 2; i++){
      int linear = i * 2048 + tid * 8;
      int row = linear >> 6, col = linear & 63;
      *(uint4*)&Bs[row][col] = *(const uint4*)&Bt[(brow0 + row) * K + k0 + col];
    }
    __syncthreads();
    #pragma unroll
    for (int kk = 0; kk < 64; kk += 32){
      short8 a[4], b[2];
      #pragma unroll
      for (int mi = 0; mi < 4; mi++) a[mi] = *(const short8*)&As[wm + mi*16 + l16][kk + quad*8];
      #pragma unroll
      for (int ni = 0; ni < 2; ni++) b[ni] = *(const short8*)&Bs[wn + ni*16 + l16][kk + quad*8];
      #pragma unroll
      for (int mi = 0; mi < 4; mi++)
        #pragma unroll
        for (int ni = 0; ni < 2; ni++)
          acc[mi][ni] = __builtin_amdgcn_mfma_f32_16x16x32_bf16(a[mi], b[ni], acc[mi][ni], 0, 0, 0);
    }
    __syncthreads();
  }

  #pragma unroll
  for (int mi = 0; mi < 4; mi++){
    #pragma unroll
    for (int reg = 0; reg < 4; reg++){
      long r = arow0 + wm + mi*16 + quad*4 + reg;   // C/D: row = quad*4+reg, col = l16
      #pragma unroll
      for (int ni = 0; ni < 2; ni++){
        int c = (int)(brow0 + wn + ni*16 + l16);
        float v = acc[mi][ni][reg] + bias[c];
        if (EPI == 0){
          Cout[r * N + c] = f2bf(v);
        } else if (EPI == 1){
          int t = nat_token((int)r);
          long idx = (long)t * C_DIM + c;
          Fout[idx] = Xres[idx] + v;
        } else if (EPI == 2){
          float g = 0.5f * v * (1.f + erff(v * 0.70710678118654752f));
          Cout[r * N + c] = f2bf(g);
        } else {
          long idx = r * C_DIM + c;
          Fout[idx] = Xres[idx] + v;
        }
      }
    }
  }
}

extern "C" void kernel_launch(void* const* d_in, const int* in_sizes, int n_in,
                              void* d_out, int out_size, void* d_ws, size_t ws_size,
                              hipStream_t stream){
  const float* x      = (const float*)d_in[0];
  const float* ln1_w  = (const float*)d_in[1];
  const float* ln1_b  = (const float*)d_in[2];
  const float* qkv_w  = (const float*)d_in[3];
  const float* qkv_b  = (const float*)d_in[4];
  const float* proj_w = (const float*)d_in[5];
  const float* proj_b = (const float*)d_in[6];
  const float* ln2_w  = (const float*)d_in[7];
  const float* ln2_b  = (const float*)d_in[8];
  const float* mlp_w1 = (const float*)d_in[9];
  const float* mlp_b1 = (const float*)d_in[10];
  const float* mlp_w2 = (const float*)d_in[11];
  const float* mlp_b2 = (const float*)d_in[12];
  float* out = (float*)d_out;   // fp32 output; also hosts fp32 residual y between EPI1 and EPI3

  // --- aliased workspace (~92.7 MiB), all internal buffers bf16 ---
  char* ws = (char*)d_ws;
  unsigned short* qkv_wt = (unsigned short*)(ws);               // [576][192]
  unsigned short* proj_wt= (unsigned short*)(ws + 221184);      // [192][192]
  unsigned short* w1t    = (unsigned short*)(ws + 294912);      // [768][192]
  unsigned short* w2t    = (unsigned short*)(ws + 589824);      // [192][768]
  unsigned short* R1     = (unsigned short*)(ws + 884736);      // 50176x192 bf16
  unsigned short* R0     = (unsigned short*)(ws + 20152320);    // up to 50176x768 bf16

  unsigned short* xw   = R1;
  unsigned short* obuf = R1;
  unsigned short* hn   = R1;
  unsigned short* qkv  = R0;
  unsigned short* hbuf = R0;

  transpose_kernel<<<(110592 + 255) / 256, 256, 0, stream>>>(qkv_w, qkv_wt, 192, 576);
  transpose_kernel<<<(36864  + 255) / 256, 256, 0, stream>>>(proj_w, proj_wt, 192, 192);
  transpose_kernel<<<(147456 + 255) / 256, 256, 0, stream>>>(mlp_w1, w1t, 192, 768);
  transpose_kernel<<<(147456 + 255) / 256, 256, 0, stream>>>(mlp_w2, w2t, 768, 192);

  ln1_kernel<<<NTOK / 4, 256, 0, stream>>>(x, ln1_w, ln1_b, xw);
  gemm_kernel<0><<<dim3(392, 9),  256, 0, stream>>>(xw, qkv_wt, qkv_b, qkv, nullptr, nullptr, 576, 192);
  attn_kernel<<<(NTOK / 49) * NHEADS / 4, 256, 0, stream>>>(qkv, obuf);
  gemm_kernel<1><<<dim3(392, 3),  256, 0, stream>>>(obuf, proj_wt, proj_b, nullptr, out, x, 192, 192);
  ln2_kernel<<<NTOK / 4, 256, 0, stream>>>(out, ln2_w, ln2_b, hn);
  gemm_kernel<2><<<dim3(392, 12), 256, 0, stream>>>(hn, w1t, mlp_b1, hbuf, nullptr, nullptr, 768, 192);
  gemm_kernel<3><<<dim3(392, 3),  256, 0, stream>>>(hbuf, w2t, mlp_b2, nullptr, out, out, 192, 768);
}

// Round 5
// 275.853 us; speedup vs baseline: 1.3378x; 1.0307x over previous
//
#include <hip/hip_runtime.h>
#include <hip/hip_bf16.h>
#include <math.h>

typedef __attribute__((ext_vector_type(8))) short short8;
typedef __attribute__((ext_vector_type(4))) float float4v;

#define C_DIM 192
#define NHEADS 6
#define NTOK 50176

__device__ __forceinline__ float bf2f(unsigned short u){
  union { unsigned int i; float f; } x; x.i = ((unsigned int)u) << 16; return x.f;
}
__device__ __forceinline__ unsigned short f2bf(float f){
  union { float f; unsigned int i; } x; x.f = f;
  unsigned int r = x.i + 0x7fff + ((x.i >> 16) & 1);
  return (unsigned short)(r >> 16);
}

// async 16B global->LDS (direct-to-shared DMA; dest = wave-uniform base + lane*16)
__device__ __forceinline__ void gload_lds16(const unsigned short* g, unsigned short* l){
  __builtin_amdgcn_global_load_lds((const __attribute__((address_space(1))) void*)g,
                                   (__attribute__((address_space(3))) void*)l, 16, 0, 0);
}

// window-layout row r -> natural token index (same mapping for LN1 gather and proj scatter)
__device__ __forceinline__ int nat_token(int r){
  int win = r / 49, n = r - win * 49;
  int b = win >> 6, rem = win & 63;
  int hs = (rem >> 3) * 7 + n / 7;
  int ws = (rem & 7) * 7 + n % 7;
  int h = hs + 3; if (h >= 56) h -= 56;
  int w = ws + 3; if (w >= 56) w -= 56;
  return (b * 56 + h) * 56 + w;
}

// ---------------- weight transpose + f32->bf16: in[R][C] fp32 -> out[C][R] bf16 ----------------
__global__ void transpose_kernel(const float* __restrict__ in,
                                 unsigned short* __restrict__ out, int R, int Cc){
  int idx = blockIdx.x * 256 + threadIdx.x;
  if (idx < R * Cc){ int r = idx / Cc, c = idx - r * Cc; out[(long)c * R + r] = f2bf(in[idx]); }
}

// ---------------- LN1 + shift + window partition (gather): fp32 in -> bf16 out ----------------
__global__ __launch_bounds__(256) void ln1_kernel(const float* __restrict__ x,
                                                  const float* __restrict__ w,
                                                  const float* __restrict__ b,
                                                  unsigned short* __restrict__ out){
  int wave = threadIdx.x >> 6, lane = threadIdx.x & 63;
  int r = blockIdx.x * 4 + wave;            // dest row, window layout
  int src = nat_token(r);
  const float* xp = x + (long)src * C_DIM;
  float v0 = xp[lane], v1 = xp[lane + 64], v2 = xp[lane + 128];
  float s = v0 + v1 + v2, s2 = v0*v0 + v1*v1 + v2*v2;
  for (int m = 32; m >= 1; m >>= 1){ s += __shfl_xor(s, m, 64); s2 += __shfl_xor(s2, m, 64); }
  float mean = s * (1.f/192.f);
  float var  = s2 * (1.f/192.f) - mean*mean;
  float rs = rsqrtf(var + 1e-5f);
  unsigned short* op = out + (long)r * C_DIM;
  op[lane]       = f2bf((v0-mean)*rs*w[lane]       + b[lane]);
  op[lane + 64]  = f2bf((v1-mean)*rs*w[lane + 64]  + b[lane + 64]);
  op[lane + 128] = f2bf((v2-mean)*rs*w[lane + 128] + b[lane + 128]);
}

// ---------------- LN2: fp32 y (in d_out, natural order) -> bf16 out ----------------
__global__ __launch_bounds__(256) void ln2_kernel(const float* __restrict__ y,
                                                  const float* __restrict__ w,
                                                  const float* __restrict__ b,
                                                  unsigned short* __restrict__ out){
  int wave = threadIdx.x >> 6, lane = threadIdx.x & 63;
  int r = blockIdx.x * 4 + wave;
  const float* yp = y + (long)r * C_DIM;
  float v0 = yp[lane], v1 = yp[lane + 64], v2 = yp[lane + 128];
  float s = v0 + v1 + v2, s2 = v0*v0 + v1*v1 + v2*v2;
  for (int m = 32; m >= 1; m >>= 1){ s += __shfl_xor(s, m, 64); s2 += __shfl_xor(s2, m, 64); }
  float mean = s * (1.f/192.f);
  float var  = s2 * (1.f/192.f) - mean*mean;
  float rs = rsqrtf(var + 1e-5f);
  unsigned short* op = out + (long)r * C_DIM;
  op[lane]       = f2bf((v0-mean)*rs*w[lane]       + b[lane]);
  op[lane + 64]  = f2bf((v1-mean)*rs*w[lane + 64]  + b[lane + 64]);
  op[lane + 128] = f2bf((v2-mean)*rs*w[lane + 128] + b[lane + 128]);
}

// ---------------- MFMA window attention: 1 wave = 1 (window, head) ----------------
__global__ __launch_bounds__(256) void attn_kernel(const unsigned short* __restrict__ qkv,
                                                   unsigned short* __restrict__ o){
  __shared__ unsigned short pbuf[4][64][72];
  int wave = threadIdx.x >> 6, lane = threadIdx.x & 63;
  int quad = lane >> 4, l16 = lane & 15;
  int wid = blockIdx.x * 4 + wave;
  int win = wid / NHEADS, head = wid - win * NHEADS;
  const unsigned short* qp = qkv + (long)win * 49 * 576 + head * 32;
  const unsigned short* kp = qp + 192;
  const unsigned short* vp = qp + 384;

  // ---- QK^T ----
  short8 qa[4], kb[4];
  #pragma unroll
  for (int mi = 0; mi < 4; mi++){
    int m = mi * 16 + l16; if (m > 48) m = 48;       // clamped rows discarded at output
    qa[mi] = *(const short8*)&qp[(long)m * 576 + quad * 8];
  }
  #pragma unroll
  for (int ni = 0; ni < 4; ni++){
    int n = ni * 16 + l16; if (n > 48) n = 48;       // clamped cols masked in softmax
    kb[ni] = *(const short8*)&kp[(long)n * 576 + quad * 8];
  }
  float4v S[4][4];
  #pragma unroll
  for (int mi = 0; mi < 4; mi++)
    #pragma unroll
    for (int ni = 0; ni < 4; ni++) S[mi][ni] = (float4v)0.f;
  #pragma unroll
  for (int mi = 0; mi < 4; mi++)
    #pragma unroll
    for (int ni = 0; ni < 4; ni++)
      S[mi][ni] = __builtin_amdgcn_mfma_f32_16x16x32_bf16(qa[mi], kb[ni], S[mi][ni], 0, 0, 0);

  // ---- softmax + P to LDS ----
  #pragma unroll
  for (int mi = 0; mi < 4; mi++){
    #pragma unroll
    for (int r = 0; r < 4; r++){
      float e[4];
      float sum = 0.f;
      #pragma unroll
      for (int ni = 0; ni < 4; ni++){
        int n = ni * 16 + l16;
        float s = S[mi][ni][r] * 0.17677669529663687f;   // 1/sqrt(32)
        s = fminf(s, 80.f);
        float ev = (n <= 48) ? __expf(s) : 0.f;
        e[ni] = ev; sum += ev;
      }
      sum += __shfl_xor(sum, 1, 64);
      sum += __shfl_xor(sum, 2, 64);
      sum += __shfl_xor(sum, 4, 64);
      sum += __shfl_xor(sum, 8, 64);
      float inv = 1.f / sum;
      int m = mi * 16 + quad * 4 + r;
      #pragma unroll
      for (int ni = 0; ni < 4; ni++)
        pbuf[wave][m][ni * 16 + l16] = f2bf(e[ni] * inv);
    }
  }
  __syncthreads();

  // ---- V^T fragments (8 scalar global loads each; rows k>48 clamped, P there = 0) ----
  short8 vb[2][2];
  #pragma unroll
  for (int kk2 = 0; kk2 < 2; kk2++){
    #pragma unroll
    for (int ni = 0; ni < 2; ni++){
      union { unsigned short us[8]; short8 v8; } u;
      #pragma unroll
      for (int j = 0; j < 8; j++){
        int k = kk2 * 32 + quad * 8 + j; if (k > 48) k = 48;
        u.us[j] = vp[(long)k * 576 + ni * 16 + l16];
      }
      vb[kk2][ni] = u.v8;
    }
  }

  // ---- PV ----
  float4v O[4][2];
  #pragma unroll
  for (int mi = 0; mi < 4; mi++)
    #pragma unroll
    for (int ni = 0; ni < 2; ni++) O[mi][ni] = (float4v)0.f;
  #pragma unroll
  for (int kk2 = 0; kk2 < 2; kk2++){
    short8 pa[4];
    #pragma unroll
    for (int mi = 0; mi < 4; mi++)
      pa[mi] = *(const short8*)&pbuf[wave][mi * 16 + l16][kk2 * 32 + quad * 8];
    #pragma unroll
    for (int mi = 0; mi < 4; mi++)
      #pragma unroll
      for (int ni = 0; ni < 2; ni++)
        O[mi][ni] = __builtin_amdgcn_mfma_f32_16x16x32_bf16(pa[mi], vb[kk2][ni], O[mi][ni], 0, 0, 0);
  }

  // ---- write O (C-layout: row=quad*4+reg+16mi, col=d=ni*16+l16) ----
  #pragma unroll
  for (int mi = 0; mi < 4; mi++){
    int m0 = mi * 16 + quad * 4;
    #pragma unroll
    for (int r = 0; r < 4; r++){
      if (m0 + r <= 48){
        #pragma unroll
        for (int ni = 0; ni < 2; ni++)
          o[((long)win * 49 + m0 + r) * C_DIM + head * 32 + ni * 16 + l16] = f2bf(O[mi][ni][r]);
      }
    }
  }
}

// ---------------- generic MFMA GEMM: A[M,K]bf16 x Bt[N,K]bf16^T + bias(fp32) ----------------
// Staging: global_load_lds width-16, XOR-swizzled LDS [row][64]:
//   physical granule pg = logical granule g ^ (row & 7)  (granule = 8 bf16 = 16B)
//   write side: lane l of chunk ci -> row = ci*8 + (l>>3), pg = l&7, g = (l&7)^(l>>3)
//   read side: b128 at [row][ (g ^ (row&7))*8 ]  -> 2-way bank aliasing only (free)
// EPI 0: qkv  -> Cout bf16 [M,N]
// EPI 1: proj -> Fout[nat(r)*192+c] = Xres[nat(r)*192+c] + acc+bias   (fp32 y into d_out)
// EPI 2: mlp1 -> Cout = bf16(gelu_tanh(acc+bias))
// EPI 3: mlp2 -> Fout[r*192+c] = Xres[r*192+c] + acc+bias  (Xres==Fout==d_out, per-elem RMW)
template<int EPI>
__global__ __launch_bounds__(256) void gemm_kernel(const unsigned short* __restrict__ A,
                                                   const unsigned short* __restrict__ Bt,
                                                   const float* __restrict__ bias,
                                                   unsigned short* __restrict__ Cout,
                                                   float* __restrict__ Fout,
                                                   const float* __restrict__ Xres,
                                                   int N, int K){
  __shared__ unsigned short As[128 * 64];
  __shared__ unsigned short Bs[64 * 64];
  int tid = threadIdx.x;
  int wave = tid >> 6, lane = tid & 63, quad = lane >> 4, l16 = lane & 15;
  int wm = (wave >> 1) * 64, wn = (wave & 1) * 32;
  int lrow = lane >> 3, lg = lane & 7;         // staging: within-chunk row, physical granule
  int gcol = (lg ^ lrow) * 8;                  // logical column (elems) this lane fetches
  float4v acc[4][2];
  #pragma unroll
  for (int i = 0; i < 4; i++)
    #pragma unroll
    for (int jj = 0; jj < 2; jj++) acc[i][jj] = (float4v)0.f;

  long arow0 = (long)blockIdx.x * 128;
  long brow0 = (long)blockIdx.y * 64;
  int sw = (l16 & 7);                          // read-side swizzle key

  for (int k0 = 0; k0 < K; k0 += 64){
    #pragma unroll
    for (int t = 0; t < 4; t++){               // A: 16 chunks x 8 rows, 4 per wave
      int ci = wave + 4 * t;
      gload_lds16(&A[(arow0 + ci * 8 + lrow) * (long)K + k0 + gcol], &As[ci * 512]);
    }
    #pragma unroll
    for (int t = 0; t < 2; t++){               // B: 8 chunks x 8 rows, 2 per wave
      int ci = wave + 4 * t;
      gload_lds16(&Bt[(brow0 + ci * 8 + lrow) * (long)K + k0 + gcol], &Bs[ci * 512]);
    }
    __syncthreads();                           // drains vmcnt (global_load_lds) + barrier
    #pragma unroll
    for (int kk8 = 0; kk8 < 8; kk8 += 4){      // kk8 = granule offset (0 or 4) = kk/8
      short8 a[4], b[2];
      #pragma unroll
      for (int mi = 0; mi < 4; mi++)
        a[mi] = *(const short8*)&As[(wm + mi*16 + l16) * 64 + ((quad + kk8) ^ sw) * 8];
      #pragma unroll
      for (int ni = 0; ni < 2; ni++)
        b[ni] = *(const short8*)&Bs[(wn + ni*16 + l16) * 64 + ((quad + kk8) ^ sw) * 8];
      #pragma unroll
      for (int mi = 0; mi < 4; mi++)
        #pragma unroll
        for (int ni = 0; ni < 2; ni++)
          acc[mi][ni] = __builtin_amdgcn_mfma_f32_16x16x32_bf16(a[mi], b[ni], acc[mi][ni], 0, 0, 0);
    }
    __syncthreads();
  }

  #pragma unroll
  for (int mi = 0; mi < 4; mi++){
    #pragma unroll
    for (int reg = 0; reg < 4; reg++){
      long r = arow0 + wm + mi*16 + quad*4 + reg;   // C/D: row = quad*4+reg, col = l16
      #pragma unroll
      for (int ni = 0; ni < 2; ni++){
        int c = (int)(brow0 + wn + ni*16 + l16);
        float v = acc[mi][ni][reg] + bias[c];
        if (EPI == 0){
          Cout[r * N + c] = f2bf(v);
        } else if (EPI == 1){
          int t = nat_token((int)r);
          long idx = (long)t * C_DIM + c;
          Fout[idx] = Xres[idx] + v;
        } else if (EPI == 2){
          // tanh-form GELU: v * sigmoid(1.5957691*v + 0.07135481*v^3); |err| < 6e-4
          float z2 = v * (1.5957691216057308f + 0.07135481282553456f * v * v);
          z2 = fminf(z2, 30.f);                // avoid exp overflow -> NaN
          float p = __expf(z2);
          float g = v * (p / (p + 1.f));
          Cout[r * N + c] = f2bf(g);
        } else {
          long idx = r * C_DIM + c;
          Fout[idx] = Xres[idx] + v;
        }
      }
    }
  }
}

extern "C" void kernel_launch(void* const* d_in, const int* in_sizes, int n_in,
                              void* d_out, int out_size, void* d_ws, size_t ws_size,
                              hipStream_t stream){
  const float* x      = (const float*)d_in[0];
  const float* ln1_w  = (const float*)d_in[1];
  const float* ln1_b  = (const float*)d_in[2];
  const float* qkv_w  = (const float*)d_in[3];
  const float* qkv_b  = (const float*)d_in[4];
  const float* proj_w = (const float*)d_in[5];
  const float* proj_b = (const float*)d_in[6];
  const float* ln2_w  = (const float*)d_in[7];
  const float* ln2_b  = (const float*)d_in[8];
  const float* mlp_w1 = (const float*)d_in[9];
  const float* mlp_b1 = (const float*)d_in[10];
  const float* mlp_w2 = (const float*)d_in[11];
  const float* mlp_b2 = (const float*)d_in[12];
  float* out = (float*)d_out;   // fp32 output; also hosts fp32 residual y between EPI1 and EPI3

  // --- aliased workspace (~92.7 MiB), all internal buffers bf16 ---
  char* ws = (char*)d_ws;
  unsigned short* qkv_wt = (unsigned short*)(ws);               // [576][192]
  unsigned short* proj_wt= (unsigned short*)(ws + 221184);      // [192][192]
  unsigned short* w1t    = (unsigned short*)(ws + 294912);      // [768][192]
  unsigned short* w2t    = (unsigned short*)(ws + 589824);      // [192][768]
  unsigned short* R1     = (unsigned short*)(ws + 884736);      // 50176x192 bf16
  unsigned short* R0     = (unsigned short*)(ws + 20152320);    // up to 50176x768 bf16

  unsigned short* xw   = R1;
  unsigned short* obuf = R1;
  unsigned short* hn   = R1;
  unsigned short* qkv  = R0;
  unsigned short* hbuf = R0;

  transpose_kernel<<<(110592 + 255) / 256, 256, 0, stream>>>(qkv_w, qkv_wt, 192, 576);
  transpose_kernel<<<(36864  + 255) / 256, 256, 0, stream>>>(proj_w, proj_wt, 192, 192);
  transpose_kernel<<<(147456 + 255) / 256, 256, 0, stream>>>(mlp_w1, w1t, 192, 768);
  transpose_kernel<<<(147456 + 255) / 256, 256, 0, stream>>>(mlp_w2, w2t, 768, 192);

  ln1_kernel<<<NTOK / 4, 256, 0, stream>>>(x, ln1_w, ln1_b, xw);
  gemm_kernel<0><<<dim3(392, 9),  256, 0, stream>>>(xw, qkv_wt, qkv_b, qkv, nullptr, nullptr, 576, 192);
  attn_kernel<<<(NTOK / 49) * NHEADS / 4, 256, 0, stream>>>(qkv, obuf);
  gemm_kernel<1><<<dim3(392, 3),  256, 0, stream>>>(obuf, proj_wt, proj_b, nullptr, out, x, 192, 192);
  ln2_kernel<<<NTOK / 4, 256, 0, stream>>>(out, ln2_w, ln2_b, hn);
  gemm_kernel<2><<<dim3(392, 12), 256, 0, stream>>>(hn, w1t, mlp_b1, hbuf, nullptr, nullptr, 768, 192);
  gemm_kernel<3><<<dim3(392, 3),  256, 0, stream>>>(hbuf, w2t, mlp_b2, nullptr, out, out, 192, 768);
}